// Round 11
// baseline (88.331 us; speedup 1.0000x reference)
//
#include <hip/hip_runtime.h>
#include <hip/hip_bf16.h>

// Spatial Transformer: B=256, C=32, H=W=64. All fp32 in/out.
// Three graph-captured kernels (no grid.sync — R10 showed coop sync overhead suspect):
//   k1 (1024 blocks): bf16 MFMA GEMM x[256,131072] @ w1^T -> partial[256][1024][32] (d_ws).
//       Block owns (kc, batch-half). w frags staged to LDS once; 8 tiles of 16 batch rows
//       via global_load_lds DMA, DOUBLE-BUFFERED: one __syncthreads per tile, DMA(t+1)
//       issued right after the barrier so it overlaps compute(t)+stores(t).
//   k2 (256 blocks): reduce partial (128 KB contiguous/block) + MLP -> theta[256][8] (d_ws).
//   k3 (2048 blocks): affine grid + bilinear sample -> d_out (8 h-rows/block).

#define K_TOT 131072
#define KC    256
#define PKN   1024                      // partial k-slots = 512 kc * 2 k-halves
#define STRB  ((size_t)PKN * 32)        // floats per batch row of partial

typedef short s16x8 __attribute__((ext_vector_type(8)));   // 8 bf16 in 4 VGPRs
typedef float f32x4 __attribute__((ext_vector_type(4)));

__device__ __forceinline__ short f2bf(float f) {
    return __builtin_bit_cast(short, __float2bfloat16(f));  // RNE; fuses to cvt_pk
}

__device__ __forceinline__ s16x8 cvt8(float4 a, float4 b) {
    s16x8 r;
    r[0] = f2bf(a.x); r[1] = f2bf(a.y); r[2] = f2bf(a.z); r[3] = f2bf(a.w);
    r[4] = f2bf(b.x); r[5] = f2bf(b.y); r[6] = f2bf(b.z); r[7] = f2bf(b.w);
    return r;
}

__device__ __forceinline__ void gload_lds16(const float* g, float* l) {
    __builtin_amdgcn_global_load_lds(
        (const __attribute__((address_space(1))) void*)(g),
        (__attribute__((address_space(3))) void*)(l),
        16, 0, 0);   // dwordx4 direct-to-LDS; dest = wave-uniform base + lane*16
}

// ===================== k1 =====================
// Decode: xcd = bid&7, q = bid>>3; kc = xcd*64 + (q>>1); half = q&1.
// Paired halves (bids differing by 8) share kc -> same XCD -> w read is L2-shared.
__global__ __launch_bounds__(256) void st_p1k(const float* __restrict__ x,
                                              const float* __restrict__ w1,
                                              float* __restrict__ partial) {
    __shared__ __align__(16) char smem[49152];
    float* xbuf0 = (float*)smem;                // [16][256] fp32 (16 KB), swizzled granules
    float* xbuf1 = (float*)(smem + 16384);      // second buffer
    s16x8* wlds  = (s16x8*)(smem + 32768);      // 1024 bf16 frags (16 KB)

    const int bid  = blockIdx.x;
    const int t    = threadIdx.x;
    const int wv   = t >> 6;
    const int lane = t & 63;
    const int m    = lane & 15;
    const int kb   = lane >> 4;
    const int jh   = wv & 1;                    // j half
    const int kh   = wv >> 1;                   // k half

    const int xcd  = bid & 7;
    const int q    = bid >> 3;                  // 0..127
    const int kc   = xcd * 64 + (q >> 1);       // 0..511, contiguous per XCD
    const int half = q & 1;                     // batch half (128 rows)
    const size_t k0 = (size_t)kc * KC;

    // prologue: issue tile-0 DMA first (flows while we cvt w), then stage w frags
    {
        const int b0 = half * 128;
#pragma unroll
        for (int i2 = 0; i2 < 4; ++i2) {
            const int r = wv * 4 + i2;
            const float* gsrc = x + (size_t)(b0 + r) * K_TOT + k0 + ((lane ^ (r & 7)) << 2);
            gload_lds16(gsrc, xbuf0 + r * 256);
        }
    }
#pragma unroll
    for (int i = 0; i < 4; ++i) {
        const int f  = i * 256 + t;
        const int fm = f & 15, fk = (f >> 4) & 3, fj = (f >> 6) & 1, fs = f >> 7;
        const float* wp = w1 + (size_t)(fj * 16 + fm) * K_TOT + k0 + fs * 32 + fk * 8;
        wlds[f] = cvt8(*(const float4*)wp, *(const float4*)(wp + 4));
    }

    const int pk = kc * 2 + kh;
    const int sw = m & 7;
#pragma unroll
    for (int it = 0; it < 8; ++it) {
        __syncthreads();   // drains DMA(it) (vmcnt0) + w ds_writes (it=0) + stores(it-1)

        // issue DMA(it+1) into the other buffer; its previous readers (tile it-1)
        // all completed before the barrier above.
        if (it < 7) {
            float* nbuf = ((it + 1) & 1) ? xbuf1 : xbuf0;
            const int b0n = half * 128 + (it + 1) * 16;
#pragma unroll
            for (int i2 = 0; i2 < 4; ++i2) {
                const int r = wv * 4 + i2;
                const float* gsrc = x + (size_t)(b0n + r) * K_TOT + k0 + ((lane ^ (r & 7)) << 2);
                gload_lds16(gsrc, nbuf + r * 256);
            }
        }

        // compute tile it (overlaps DMA(it+1))
        const float* cbuf = (it & 1) ? xbuf1 : xbuf0;
        const float* xr = cbuf + m * 256;
        f32x4 acc = {0.f, 0.f, 0.f, 0.f};
#pragma unroll
        for (int sss = 0; sss < 4; ++sss) {
            const int gb = kh * 32 + sss * 8 + kb * 2;     // 16B granule index of k
            const float4 fa = *(const float4*)(xr + ((gb ^ sw) << 2));
            const float4 fb = *(const float4*)(xr + (((gb + 1) ^ sw) << 2));
            const s16x8 af = cvt8(fa, fb);
            const s16x8 bf = wlds[((kh * 4 + sss) * 2 + jh) * 64 + lane];
            acc = __builtin_amdgcn_mfma_f32_16x16x32_bf16(af, bf, acc, 0, 0, 0);
        }
        // C/D: col(j)=m, row(b within 16)=kb*4+rr
        const int b0 = half * 128 + it * 16;
        float* p0 = partial + (size_t)(b0 + kb * 4) * STRB + (size_t)pk * 32 + jh * 16 + m;
#pragma unroll
        for (int rr = 0; rr < 4; ++rr)
            p0[(size_t)rr * STRB] = acc[rr];
    }
}

// ===================== k2 =====================
__global__ __launch_bounds__(256) void st_p2k(const float* __restrict__ partial,
                                              const float* __restrict__ b1,
                                              const float* __restrict__ w2,
                                              const float* __restrict__ b2,
                                              const float* __restrict__ w3,
                                              const float* __restrict__ b3,
                                              float* __restrict__ theta) {
    const int b = blockIdx.x;
    const int t = threadIdx.x;
    const float* pb = partial + (size_t)b * STRB;       // 128 KB contiguous

    float4 v = {0.f, 0.f, 0.f, 0.f};
#pragma unroll
    for (int i = 0; i < 32; ++i) {                      // j-class of thread t = (4t)&31
        const float4 u = *(const float4*)(pb + (size_t)(i * 256 + t) * 4);
        v.x += u.x; v.y += u.y; v.z += u.z; v.w += u.w;
    }

    __shared__ float4 red[256];
    __shared__ float s1s[32];
    __shared__ float s2s[32];
    red[t] = v;
    __syncthreads();
#pragma unroll
    for (int off = 128; off >= 8; off >>= 1) {          // offsets %8==0 preserve j-class
        if (t < off) {
            float4 a = red[t];
            const float4 c = red[t + off];
            a.x += c.x; a.y += c.y; a.z += c.z; a.w += c.w;
            red[t] = a;
        }
        __syncthreads();
    }
    if (t < 8) {                                        // thread t holds j-quad 4t..4t+3
        const float4 qd = red[t];
        s1s[4 * t + 0] = fmaxf(qd.x + b1[4 * t + 0], 0.f);
        s1s[4 * t + 1] = fmaxf(qd.y + b1[4 * t + 1], 0.f);
        s1s[4 * t + 2] = fmaxf(qd.z + b1[4 * t + 2], 0.f);
        s1s[4 * t + 3] = fmaxf(qd.w + b1[4 * t + 3], 0.f);
    }
    __syncthreads();
    if (t < 32) {
        float vv = b2[t];
#pragma unroll
        for (int i = 0; i < 32; ++i) vv += w2[t * 32 + i] * s1s[i];
        s2s[t] = fmaxf(vv, 0.f);
    }
    __syncthreads();
    if (t < 8) {
        float vv = 0.f;
        if (t < 6) {
            vv = b3[t];
#pragma unroll
            for (int i = 0; i < 32; ++i) vv += w3[t * 32 + i] * s2s[i];
        }
        theta[b * 8 + t] = vv;
    }
}

// ===================== k3 =====================
__global__ __launch_bounds__(256) void st_p3k(const float* __restrict__ x,
                                              const float* __restrict__ theta,
                                              float* __restrict__ out) {
    const int bid = blockIdx.x;                 // 0..2047
    const int b   = bid >> 3;
    const int h0  = (bid & 7) * 8;
    const int t   = threadIdx.x;
    const int w   = t & 63;
    const int c0  = t >> 6;

    const float* tb = theta + b * 8;
    const float t0 = tb[0], t1 = tb[1], t2 = tb[2];
    const float t3 = tb[3], t4 = tb[4], t5 = tb[5];

    for (int r = 0; r < 8; ++r) {
        const int h = h0 + r;
        const float xs = ((float)w - 31.5f) * 0.03125f;
        const float ys = ((float)h - 31.5f) * 0.03125f;
        const float gxn = fmaf(t1, ys, fmaf(t0, xs, t2));
        const float gyn = fmaf(t4, ys, fmaf(t3, xs, t5));
        const float gx = fmaf(gxn, 32.f, 31.5f);
        const float gy = fmaf(gyn, 32.f, 31.5f);
        const float x0f = floorf(gx), y0f = floorf(gy);
        const float wx1 = gx - x0f, wx0 = 1.f - wx1;
        const float wy1 = gy - y0f, wy0 = 1.f - wy1;
        const int ix = (int)x0f, iy = (int)y0f;
        const bool vx0 = (ix >= 0) && (ix < 64);
        const bool vx1 = (ix >= -1) && (ix < 63);
        const bool vy0 = (iy >= 0) && (iy < 64);
        const bool vy1 = (iy >= -1) && (iy < 63);
        const int cx0 = min(max(ix, 0), 63);
        const int cx1 = min(max(ix + 1, 0), 63);
        const int cy0 = min(max(iy, 0), 63);
        const int cy1 = min(max(iy + 1, 0), 63);
        const float w00 = wx0 * wy0 * ((vx0 && vy0) ? 1.f : 0.f);
        const float w10 = wx1 * wy0 * ((vx1 && vy0) ? 1.f : 0.f);
        const float w01 = wx0 * wy1 * ((vx0 && vy1) ? 1.f : 0.f);
        const float w11 = wx1 * wy1 * ((vx1 && vy1) ? 1.f : 0.f);
        const int r0 = cy0 * 64, r1 = cy1 * 64;
#pragma unroll
        for (int i = 0; i < 8; ++i) {
            const int c = c0 + 4 * i;
            const float* img = x + (((size_t)b * 32 + c) << 12);
            const float v = w00 * img[r0 + cx0] + w10 * img[r0 + cx1]
                          + w01 * img[r1 + cx0] + w11 * img[r1 + cx1];
            __builtin_nontemporal_store(v, &out[(((size_t)b * 32 + c) << 12) + h * 64 + w]);
        }
    }
}

extern "C" void kernel_launch(void* const* d_in, const int* in_sizes, int n_in,
                              void* d_out, int out_size, void* d_ws, size_t ws_size,
                              hipStream_t stream) {
    const float* x  = (const float*)d_in[0];
    const float* w1 = (const float*)d_in[1];
    const float* b1 = (const float*)d_in[2];
    const float* w2 = (const float*)d_in[3];
    const float* b2 = (const float*)d_in[4];
    const float* w3 = (const float*)d_in[5];
    const float* b3 = (const float*)d_in[6];
    float* out = (float*)d_out;
    float* ws  = (float*)d_ws;                       // partial 33.5 MB + theta 2 KB
    float* partial = ws;
    float* theta   = ws + (size_t)256 * STRB;

    st_p1k<<<1024, 256, 0, stream>>>(x, w1, partial);
    st_p2k<<<256, 256, 0, stream>>>(partial, b1, w2, b2, w3, b3, theta);
    st_p3k<<<2048, 256, 0, stream>>>(x, theta, out);
}

// Round 12
// 87.878 us; speedup vs baseline: 1.0052x; 1.0052x over previous
//
#include <hip/hip_runtime.h>
#include <hip/hip_bf16.h>

// Spatial Transformer: B=256, C=32, H=W=64. All fp32 in/out.
// Three graph-captured kernels:
//   k1 (1024 blocks): bf16 MFMA GEMM x[256,131072] @ w1^T -> partial[256][1024][32] (d_ws).
//       T3/T4 pipeline: 3 rotating LDS x-buffers (16 KB each), global_load_lds DMA with
//       prefetch depth 2, raw s_barrier + counted s_waitcnt vmcnt(N) (never 0 mid-loop).
//       w fragments live in REGISTERS (per-wave quadrant), not LDS.
//   k2 (256 blocks): reduce partial (128 KB contiguous/block) + MLP -> theta[256][8] (d_ws).
//   k3 (2048 blocks): affine grid + bilinear sample -> d_out (8 h-rows/block).

#define K_TOT 131072
#define KC    256
#define PKN   1024                      // partial k-slots = 512 kc * 2 k-halves
#define STRB  ((size_t)PKN * 32)        // floats per batch row of partial

typedef short s16x8 __attribute__((ext_vector_type(8)));   // 8 bf16 in 4 VGPRs
typedef float f32x4 __attribute__((ext_vector_type(4)));

__device__ __forceinline__ short f2bf(float f) {
    return __builtin_bit_cast(short, __float2bfloat16(f));  // RNE; fuses to cvt_pk
}

__device__ __forceinline__ s16x8 cvt8(float4 a, float4 b) {
    s16x8 r;
    r[0] = f2bf(a.x); r[1] = f2bf(a.y); r[2] = f2bf(a.z); r[3] = f2bf(a.w);
    r[4] = f2bf(b.x); r[5] = f2bf(b.y); r[6] = f2bf(b.z); r[7] = f2bf(b.w);
    return r;
}

__device__ __forceinline__ void gload_lds16(const float* g, float* l) {
    __builtin_amdgcn_global_load_lds(
        (const __attribute__((address_space(1))) void*)(g),
        (__attribute__((address_space(3))) void*)(l),
        16, 0, 0);   // dwordx4 direct-to-LDS; dest = wave-uniform base + lane*16
}

// ===================== k1 =====================
// Decode: xcd = bid&7, q = bid>>3; kc = xcd*64 + (q>>1); half = q&1.
// Paired halves (bids differing by 8) share kc -> same XCD -> w read L2-shared.
__global__ __launch_bounds__(256) void st_p1k(const float* __restrict__ x,
                                              const float* __restrict__ w1,
                                              float* __restrict__ partial) {
    __shared__ __align__(16) float xbuf[3][16 * KC];   // 3 x 16 KB, swizzled granules

    const int bid  = blockIdx.x;
    const int t    = threadIdx.x;
    const int wv   = t >> 6;
    const int lane = t & 63;
    const int m    = lane & 15;
    const int kb   = lane >> 4;
    const int jh   = wv & 1;                    // j half (16 j's)
    const int kh   = wv >> 1;                   // k half (128 k)

    const int xcd  = bid & 7;
    const int q    = bid >> 3;                  // 0..127
    const int kc   = xcd * 64 + (q >> 1);       // 0..511, contiguous per XCD
    const int half = q & 1;                     // batch half (128 rows)
    const size_t k0 = (size_t)kc * KC;

    // ---- w fragments in registers: this wave's (jh, kh) quadrant, 4 frags.
    // B-frag (sss): lane (m=j, kb): w1[jh*16+m][k0 + (kh*4+sss)*32 + kb*8 ..+8]
    const float* wq = w1 + (size_t)(jh * 16 + m) * K_TOT + k0 + (size_t)kh * 128 + kb * 8;
    float4 wr[8];
#pragma unroll
    for (int sss = 0; sss < 4; ++sss) {
        wr[2 * sss]     = *(const float4*)(wq + sss * 32);
        wr[2 * sss + 1] = *(const float4*)(wq + sss * 32 + 4);
    }

    // ---- prologue DMA: tiles 0 and 1 (depth-2). 4 instrs/wave/tile.
#pragma unroll
    for (int pt = 0; pt < 2; ++pt) {
#pragma unroll
        for (int i2 = 0; i2 < 4; ++i2) {
            const int r = wv * 4 + i2;
            const int b0 = half * 128 + pt * 16;
            const float* gsrc = x + (size_t)(b0 + r) * K_TOT + k0 + ((lane ^ (r & 7)) << 2);
            gload_lds16(gsrc, &xbuf[pt][r * KC]);
        }
    }

    // w cvt (the implicit vmcnt wait for wq data also covers nothing newer needed)
    s16x8 wf[4];
#pragma unroll
    for (int sss = 0; sss < 4; ++sss) wf[sss] = cvt8(wr[2 * sss], wr[2 * sss + 1]);

    const int pk = kc * 2 + kh;
    const int sw = m & 7;

    // vmcnt stream per wave/iter: D(it+2)[4] ... stores(it)[4]. Exact counts:
    // it0: newer-than-D0 = D1(4)                    -> vmcnt(4)
    // it1: newer-than-D1 = D2(4)+st0(4)             -> vmcnt(8)
    // 2<=it<=6: newer = st(it-2)+D(it+1)+st(it-1)   -> vmcnt(12)
    // it7: newer = st5(4)+st6(4)                    -> vmcnt(8)
#pragma unroll
    for (int it = 0; it < 8; ++it) {
        if (it == 0)              asm volatile("s_waitcnt vmcnt(4)"  ::: "memory");
        else if (it == 1 || it == 7) asm volatile("s_waitcnt vmcnt(8)"  ::: "memory");
        else                      asm volatile("s_waitcnt vmcnt(12)" ::: "memory");
        __builtin_amdgcn_s_barrier();           // raw barrier: no vmcnt(0) drain
        __builtin_amdgcn_sched_barrier(0);      // fence: no ds_read hoisting above

        // prefetch tile it+2 into buf[(it+2)%3] (its readers passed the barrier above)
        if (it + 2 < 8) {
            float* nbuf = xbuf[(it + 2) % 3];
            const int b0n = half * 128 + (it + 2) * 16;
#pragma unroll
            for (int i2 = 0; i2 < 4; ++i2) {
                const int r = wv * 4 + i2;
                const float* gsrc = x + (size_t)(b0n + r) * K_TOT + k0 + ((lane ^ (r & 7)) << 2);
                gload_lds16(gsrc, nbuf + r * KC);
            }
        }

        // compute tile it
        const float* xr = &xbuf[it % 3][m * KC];
        f32x4 acc = {0.f, 0.f, 0.f, 0.f};
#pragma unroll
        for (int sss = 0; sss < 4; ++sss) {
            const int gb = kh * 32 + sss * 8 + kb * 2;     // 16B granule index of k
            const float4 fa = *(const float4*)(xr + ((gb ^ sw) << 2));
            const float4 fb = *(const float4*)(xr + (((gb + 1) ^ sw) << 2));
            const s16x8 af = cvt8(fa, fb);
            acc = __builtin_amdgcn_mfma_f32_16x16x32_bf16(af, wf[sss], acc, 0, 0, 0);
        }

        // C/D: col(j)=m, row(b within 16)=kb*4+rr  -> 4 store instrs (64 B lines)
        const int b0 = half * 128 + it * 16;
        float* p0 = partial + (size_t)(b0 + kb * 4) * STRB + (size_t)pk * 32 + jh * 16 + m;
#pragma unroll
        for (int rr = 0; rr < 4; ++rr)
            p0[(size_t)rr * STRB] = acc[rr];
    }
}

// ===================== k2 =====================
__global__ __launch_bounds__(256) void st_p2k(const float* __restrict__ partial,
                                              const float* __restrict__ b1,
                                              const float* __restrict__ w2,
                                              const float* __restrict__ b2,
                                              const float* __restrict__ w3,
                                              const float* __restrict__ b3,
                                              float* __restrict__ theta) {
    const int b = blockIdx.x;
    const int t = threadIdx.x;
    const float* pb = partial + (size_t)b * STRB;       // 128 KB contiguous

    float4 v = {0.f, 0.f, 0.f, 0.f};
#pragma unroll
    for (int i = 0; i < 32; ++i) {                      // j-class of thread t = (4t)&31
        const float4 u = *(const float4*)(pb + (size_t)(i * 256 + t) * 4);
        v.x += u.x; v.y += u.y; v.z += u.z; v.w += u.w;
    }

    __shared__ float4 red[256];
    __shared__ float s1s[32];
    __shared__ float s2s[32];
    red[t] = v;
    __syncthreads();
#pragma unroll
    for (int off = 128; off >= 8; off >>= 1) {          // offsets %8==0 preserve j-class
        if (t < off) {
            float4 a = red[t];
            const float4 c = red[t + off];
            a.x += c.x; a.y += c.y; a.z += c.z; a.w += c.w;
            red[t] = a;
        }
        __syncthreads();
    }
    if (t < 8) {                                        // thread t holds j-quad 4t..4t+3
        const float4 qd = red[t];
        s1s[4 * t + 0] = fmaxf(qd.x + b1[4 * t + 0], 0.f);
        s1s[4 * t + 1] = fmaxf(qd.y + b1[4 * t + 1], 0.f);
        s1s[4 * t + 2] = fmaxf(qd.z + b1[4 * t + 2], 0.f);
        s1s[4 * t + 3] = fmaxf(qd.w + b1[4 * t + 3], 0.f);
    }
    __syncthreads();
    if (t < 32) {
        float vv = b2[t];
#pragma unroll
        for (int i = 0; i < 32; ++i) vv += w2[t * 32 + i] * s1s[i];
        s2s[t] = fmaxf(vv, 0.f);
    }
    __syncthreads();
    if (t < 8) {
        float vv = 0.f;
        if (t < 6) {
            vv = b3[t];
#pragma unroll
            for (int i = 0; i < 32; ++i) vv += w3[t * 32 + i] * s2s[i];
        }
        theta[b * 8 + t] = vv;
    }
}

// ===================== k3 =====================
__global__ __launch_bounds__(256) void st_p3k(const float* __restrict__ x,
                                              const float* __restrict__ theta,
                                              float* __restrict__ out) {
    const int bid = blockIdx.x;                 // 0..2047
    const int b   = bid >> 3;
    const int h0  = (bid & 7) * 8;
    const int t   = threadIdx.x;
    const int w   = t & 63;
    const int c0  = t >> 6;

    const float* tb = theta + b * 8;
    const float t0 = tb[0], t1 = tb[1], t2 = tb[2];
    const float t3 = tb[3], t4 = tb[4], t5 = tb[5];

    for (int r = 0; r < 8; ++r) {
        const int h = h0 + r;
        const float xs = ((float)w - 31.5f) * 0.03125f;
        const float ys = ((float)h - 31.5f) * 0.03125f;
        const float gxn = fmaf(t1, ys, fmaf(t0, xs, t2));
        const float gyn = fmaf(t4, ys, fmaf(t3, xs, t5));
        const float gx = fmaf(gxn, 32.f, 31.5f);
        const float gy = fmaf(gyn, 32.f, 31.5f);
        const float x0f = floorf(gx), y0f = floorf(gy);
        const float wx1 = gx - x0f, wx0 = 1.f - wx1;
        const float wy1 = gy - y0f, wy0 = 1.f - wy1;
        const int ix = (int)x0f, iy = (int)y0f;
        const bool vx0 = (ix >= 0) && (ix < 64);
        const bool vx1 = (ix >= -1) && (ix < 63);
        const bool vy0 = (iy >= 0) && (iy < 64);
        const bool vy1 = (iy >= -1) && (iy < 63);
        const int cx0 = min(max(ix, 0), 63);
        const int cx1 = min(max(ix + 1, 0), 63);
        const int cy0 = min(max(iy, 0), 63);
        const int cy1 = min(max(iy + 1, 0), 63);
        const float w00 = wx0 * wy0 * ((vx0 && vy0) ? 1.f : 0.f);
        const float w10 = wx1 * wy0 * ((vx1 && vy0) ? 1.f : 0.f);
        const float w01 = wx0 * wy1 * ((vx0 && vy1) ? 1.f : 0.f);
        const float w11 = wx1 * wy1 * ((vx1 && vy1) ? 1.f : 0.f);
        const int r0 = cy0 * 64, r1 = cy1 * 64;
#pragma unroll
        for (int i = 0; i < 8; ++i) {
            const int c = c0 + 4 * i;
            const float* img = x + (((size_t)b * 32 + c) << 12);
            const float v = w00 * img[r0 + cx0] + w10 * img[r0 + cx1]
                          + w01 * img[r1 + cx0] + w11 * img[r1 + cx1];
            __builtin_nontemporal_store(v, &out[(((size_t)b * 32 + c) << 12) + h * 64 + w]);
        }
    }
}

extern "C" void kernel_launch(void* const* d_in, const int* in_sizes, int n_in,
                              void* d_out, int out_size, void* d_ws, size_t ws_size,
                              hipStream_t stream) {
    const float* x  = (const float*)d_in[0];
    const float* w1 = (const float*)d_in[1];
    const float* b1 = (const float*)d_in[2];
    const float* w2 = (const float*)d_in[3];
    const float* b2 = (const float*)d_in[4];
    const float* w3 = (const float*)d_in[5];
    const float* b3 = (const float*)d_in[6];
    float* out = (float*)d_out;
    float* ws  = (float*)d_ws;                       // partial 33.5 MB + theta 2 KB
    float* partial = ws;
    float* theta   = ws + (size_t)256 * STRB;

    st_p1k<<<1024, 256, 0, stream>>>(x, w1, partial);
    st_p2k<<<256, 256, 0, stream>>>(partial, b1, w2, b2, w3, b3, theta);
    st_p3k<<<2048, 256, 0, stream>>>(x, theta, out);
}